// Round 21
// baseline (3861.260 us; speedup 1.0000x reference)
//
#include <hip/hip_runtime.h>

#define T_STEPS 8192
#define BATCH   128
#define HID     96
#define BT      4                  // batch tile per block
#define NBLK    (BATCH / BT)       // 32 blocks

typedef unsigned int u32;
typedef u32   u32x4 __attribute__((ext_vector_type(4)));
typedef float f32x4 __attribute__((ext_vector_type(4)));
typedef __fp16 h2_t __attribute__((ext_vector_type(2)));

#define L2E 1.4426950408889634f
#define K2  2.8853900817779268f   // 2*log2(e)

__device__ __forceinline__ u32 pk2(float a, float b) {
    return __builtin_bit_cast(u32, __builtin_amdgcn_cvt_pkrtz(a, b));
}
__device__ __forceinline__ float fdot2u(u32 w, u32 h, float acc) {
    return __builtin_amdgcn_fdot2(__builtin_bit_cast(h2_t, w),
                                  __builtin_bit_cast(h2_t, h), acc, false);
}
// preacts arrive PRE-SCALED by log2e (2log2e for g/cell): exp2 direct
__device__ __forceinline__ float sig2(float v) {
    return __builtin_amdgcn_rcpf(1.0f + __builtin_amdgcn_exp2f(-v));
}
__device__ __forceinline__ float tanh2(float v) {
    return fmaf(2.0f, __builtin_amdgcn_rcpf(1.0f + __builtin_amdgcn_exp2f(-v)), -1.0f);
}

// fresh-accumulator MFMA: D = A*B + Z (Z = pinned zero quad). All 12 are
// INDEPENDENT -> MFMA dep-chain depth 1 (R20 chained depth 3: ~2 extra MFMA
// latencies on the recurrence's critical path). k-sums combined on VALU.
#define MFMA_Z(D, AF, BF, Z) \
    asm("v_mfma_f32_16x16x32_f16 %0, %1, %2, %3" : "=v"(D) : "v"(AF), "a"(BF), "v"(Z))

// LDS-only barrier (R15-R20 proven)
#define LBAR() asm volatile("s_waitcnt lgkmcnt(0)\n\ts_barrier" ::: "memory")

// ---- prepack W_hh -> f16 MFMA B-frags (R12-verified mapping) + exp2 prescale ----
__global__ void prepack_kernel(const float* __restrict__ W_hh, u32* __restrict__ wpk) {
    const int i = blockIdx.x * blockDim.x + threadIdx.x;
    if (i < 384 * 48) {
        const int r   = i & 3;
        const int u4  = i >> 2;
        const int tid = u4 / 12;
        const int f   = u4 % 12;
        const int g = f / 3, s = f % 3;
        const int l = tid & 63, u = tid >> 6;
        const int n = g * HID + u * 16 + (l & 15);
        const int k = s * 32 + ((l >> 4) & 3) * 8 + 2 * r;
        const float sc = (g == 2) ? K2 : L2E;
        wpk[i] = pk2(W_hh[n * HID + k] * sc, W_hh[n * HID + k + 1] * sc);
    }
}

__global__ __attribute__((amdgpu_flat_work_group_size(448, 448), amdgpu_waves_per_eu(1, 2)))
void lstm_mfma_kernel(const float* __restrict__ x,
                      const float* __restrict__ W_ih,
                      const float* __restrict__ b_ih,
                      const float* __restrict__ b_hh,
                      const float* __restrict__ W_fc,
                      const float* __restrict__ b_fc,
                      const u32x4* __restrict__ wpk4,
                      float* __restrict__ out)
{
    const int bo  = blockIdx.x * BT;
    const int tid = threadIdx.x;            // waves 0-5 workers, wave 6 FC
    const int l = tid & 63, u = tid >> 6;
    const bool isW = tid < 384;
    const int lg = l >> 4;                  // worker: k-subgroup / epilogue batch

    __shared__ __align__(16) __fp16 hbuf[2][BT][104];   // h state, row-pad 104
    __shared__ __align__(16) float  xs[2][BT];
    __shared__ __align__(16) float  fcp[BT][4];         // FC 4-way partials (same-step)

    for (int i = tid; i < 2 * BT * 104 / 2; i += 448) ((u32*)hbuf)[i] = 0u;
    if (tid < BT * 4) ((float*)fcp)[tid] = 0.0f;
    if (tid < BT) xs[0][tid] = x[bo + tid];

    const int jw = isW ? (u * 16 + (l & 15)) : 0;

    // B-frags: load once, pin to AGPRs (R12-proven residency)
    const u32x4* wp = wpk4 + (isW ? tid * 12 : 0);
    u32x4 b0 = wp[0], b1 = wp[1], b2  = wp[2],  b3  = wp[3];
    u32x4 b4 = wp[4], b5 = wp[5], b6  = wp[6],  b7  = wp[7];
    u32x4 b8 = wp[8], b9 = wp[9], b10 = wp[10], b11 = wp[11];
    asm volatile("" : "+a"(b0));  asm volatile("" : "+a"(b1));
    asm volatile("" : "+a"(b2));  asm volatile("" : "+a"(b3));
    asm volatile("" : "+a"(b4));  asm volatile("" : "+a"(b5));
    asm volatile("" : "+a"(b6));  asm volatile("" : "+a"(b7));
    asm volatile("" : "+a"(b8));  asm volatile("" : "+a"(b9));
    asm volatile("" : "+a"(b10)); asm volatile("" : "+a"(b11));

    // x-weights / biases, prescaled per gate (i,f,o: log2e; g: 2log2e)
    f32x4 wih4 = { W_ih[0*HID+jw] * L2E, W_ih[1*HID+jw] * L2E,
                   W_ih[2*HID+jw] * K2,  W_ih[3*HID+jw] * L2E };
    f32x4 bs4  = { (b_ih[0*HID+jw] + b_hh[0*HID+jw]) * L2E,
                   (b_ih[1*HID+jw] + b_hh[1*HID+jw]) * L2E,
                   (b_ih[2*HID+jw] + b_hh[2*HID+jw]) * K2,
                   (b_ih[3*HID+jw] + b_hh[3*HID+jw]) * L2E };
    asm volatile("" : "+v"(wih4)); asm volatile("" : "+v"(bs4));
    const float bfc = b_fc[0];

    // pinned zero quad: fresh-acc MFMA C-operand
    f32x4 zq = {0.f, 0.f, 0.f, 0.f};
    asm volatile("" : "+v"(zq));

    // FC wave: fm = l>>4 (batch), fp = l&15 (col group of 6 f16) -- R19 layout
    const int fm = l >> 4, fp = l & 15;
    u32 wf0 = 0, wf1 = 0, wf2 = 0;
    if (!isW) {
        wf0 = pk2(W_fc[fp*6+0], W_fc[fp*6+1]);
        wf1 = pk2(W_fc[fp*6+2], W_fc[fp*6+3]);
        wf2 = pk2(W_fc[fp*6+4], W_fc[fp*6+5]);
    }

    float c = 0.0f;                         // scaled cell state, batch lg, unit jw

    // parity-constant LDS pointers (R20)
    const __fp16* hr0 = &hbuf[0][(l & 15) >> 2][lg * 8];
    const __fp16* hr1 = &hbuf[1][(l & 15) >> 2][lg * 8];
    __fp16* hw0 = &hbuf[1][lg][jw];
    __fp16* hw1 = &hbuf[0][lg][jw];
    const u32* fr0 = (const u32*)&hbuf[0][fm][0] + fp * 3;
    const u32* fr1 = (const u32*)&hbuf[1][fm][0] + fp * 3;

    // FC x shift-chain: xO=x[t-1], xC=x[t], xP=x[t+1]
    float xO = 0.f, xC = 0.f, xP = 0.f;
    if (!isW) { xC = x[bo + fm]; xP = x[BATCH + bo + fm]; }
    __syncthreads();

#define WORK_BODY(P)                                                              \
    {                                                                             \
        const float xm = xs[P][lg];                                               \
        const __fp16* hr = (P) ? hr1 : hr0;                                       \
        const u32x4 a0 = *(const u32x4*)(hr);                                     \
        const u32x4 a1 = *(const u32x4*)(hr + 32);                                \
        const u32x4 a2 = *(const u32x4*)(hr + 64);                                \
        const float e0 = fmaf(xm, wih4[0], bs4[0]);                               \
        const float e1 = fmaf(xm, wih4[1], bs4[1]);                               \
        const float e2 = fmaf(xm, wih4[2], bs4[2]);                               \
        const float e3 = fmaf(xm, wih4[3], bs4[3]);                               \
        f32x4 q0, q1, q2, q3, q4, q5, q6, q7, q8, q9, q10, q11;                   \
        __builtin_amdgcn_s_setprio(1);                                            \
        MFMA_Z(q0, a0, b0, zq);  MFMA_Z(q1, a0, b3, zq);                          \
        MFMA_Z(q2, a0, b6, zq);  MFMA_Z(q3, a0, b9, zq);                          \
        MFMA_Z(q4, a1, b1, zq);  MFMA_Z(q5, a1, b4, zq);                          \
        MFMA_Z(q6, a1, b7, zq);  MFMA_Z(q7, a1, b10, zq);                         \
        MFMA_Z(q8, a2, b2, zq);  MFMA_Z(q9, a2, b5, zq);                          \
        MFMA_Z(q10, a2, b8, zq); MFMA_Z(q11, a2, b11, zq);                        \
        __builtin_amdgcn_s_setprio(0);                                            \
        asm volatile("s_nop 7");                                                  \
        const float pi = (q0[0] + q4[0]) + (q8[0]  + e0);                         \
        const float pf = (q1[0] + q5[0]) + (q9[0]  + e1);                         \
        const float pg = (q2[0] + q6[0]) + (q10[0] + e2);                         \
        const float po = (q3[0] + q7[0]) + (q11[0] + e3);                         \
        const float gi = sig2(pi);                                                \
        const float gf = sig2(pf);                                                \
        const float gg = tanh2(pg);                                               \
        const float go = sig2(po);                                                \
        c = fmaf(gf, c, gi * gg * K2);                                            \
        const float hn = go * tanh2(c);                                           \
        *((P) ? hw1 : hw0) = (__fp16)hn;                                          \
    }

#define FC_BODY(P, T)                                                             \
    {                                                                             \
        if ((T) > 0) {                                                            \
            const u32* hp = (P) ? fr1 : fr0;                                      \
            const u32 hA = hp[0], hB = hp[1], hC = hp[2];                         \
            float s0 = fdot2u(wf0, hA, 0.0f);                                     \
            float s1 = fdot2u(wf1, hB, 0.0f);                                     \
            float s2 = fdot2u(wf2, hC, 0.0f);                                     \
            float p = (s0 + s1) + s2;                                             \
            p += __shfl_xor(p, 1);          /* DPP quad_perm */                   \
            p += __shfl_xor(p, 2);          /* DPP quad_perm */                   \
            if ((fp & 3) == 0) fcp[fm][fp >> 2] = p;                              \
            asm volatile("s_waitcnt lgkmcnt(0)" ::: "memory");                    \
            if (fp == 0) {                                                        \
                const float s = (fcp[fm][0] + fcp[fm][1]) + (fcp[fm][2] + fcp[fm][3]); \
                out[((T) - 1) * BATCH + bo + fm] = s + bfc + xO;                  \
            }                                                                     \
        }                                                                         \
        if (fp == 0) xs[(P) ^ 1][fm] = xP;                                        \
        xO = xC; xC = xP;                                                         \
        const int tn = ((T) + 2 < T_STEPS) ? ((T) + 2) : (T_STEPS - 1);           \
        xP = x[tn * BATCH + bo + fm];                                             \
    }

    for (int t = 0; t < T_STEPS; t += 2) {
        if (isW) WORK_BODY(0) else FC_BODY(0, t)
        LBAR();
        if (isW) WORK_BODY(1) else FC_BODY(1, t + 1)
        LBAR();
    }

    if (!isW) {   // tail: out[T-1] from h_T (hbuf[0]); xO = x[T-1]
        const u32 hA = fr0[0], hB = fr0[1], hC = fr0[2];
        float s0 = fdot2u(wf0, hA, 0.0f);
        float s1 = fdot2u(wf1, hB, 0.0f);
        float s2 = fdot2u(wf2, hC, 0.0f);
        float p = (s0 + s1) + s2;
        p += __shfl_xor(p, 1);
        p += __shfl_xor(p, 2);
        if ((fp & 3) == 0) fcp[fm][fp >> 2] = p;
        asm volatile("s_waitcnt lgkmcnt(0)" ::: "memory");
        if (fp == 0) {
            const float s = (fcp[fm][0] + fcp[fm][1]) + (fcp[fm][2] + fcp[fm][3]);
            out[(T_STEPS - 1) * BATCH + bo + fm] = s + bfc + xO;
        }
    }
}

extern "C" void kernel_launch(void* const* d_in, const int* in_sizes, int n_in,
                              void* d_out, int out_size, void* d_ws, size_t ws_size,
                              hipStream_t stream) {
    (void)in_sizes; (void)n_in; (void)out_size; (void)ws_size;
    const float* x    = (const float*)d_in[0];
    const float* W_ih = (const float*)d_in[1];
    const float* W_hh = (const float*)d_in[2];
    const float* b_ih = (const float*)d_in[3];
    const float* b_hh = (const float*)d_in[4];
    const float* W_fc = (const float*)d_in[5];
    const float* b_fc = (const float*)d_in[6];
    float* out = (float*)d_out;
    u32* wpk = (u32*)d_ws;                          // 384*48 u32 = 73728 B

    prepack_kernel<<<dim3((384 * 48 + 255) / 256), dim3(256), 0, stream>>>(W_hh, wpk);

    lstm_mfma_kernel<<<dim3(NBLK), dim3(448), 0, stream>>>(
        x, W_ih, b_ih, b_hh, W_fc, b_fc, (const u32x4*)wpk, out);
}

// Round 22
// 3627.188 us; speedup vs baseline: 1.0645x; 1.0645x over previous
//
#include <hip/hip_runtime.h>

#define T_STEPS 8192
#define BATCH   128
#define HID     96
#define BT      4                  // batch tile per block
#define NBLK    (BATCH / BT)       // 32 blocks

typedef unsigned int u32;
typedef u32   u32x4 __attribute__((ext_vector_type(4)));
typedef float f32x4 __attribute__((ext_vector_type(4)));
typedef __fp16 h2_t __attribute__((ext_vector_type(2)));

#define L2E 1.4426950408889634f
#define K2  2.8853900817779268f   // 2*log2(e)

__device__ __forceinline__ u32 pk2(float a, float b) {
    return __builtin_bit_cast(u32, __builtin_amdgcn_cvt_pkrtz(a, b));
}
__device__ __forceinline__ float fdot2u(u32 w, u32 h, float acc) {
    return __builtin_amdgcn_fdot2(__builtin_bit_cast(h2_t, w),
                                  __builtin_bit_cast(h2_t, h), acc, false);
}
// preacts arrive PRE-SCALED by log2e (2log2e for g/cell): exp2 direct
__device__ __forceinline__ float sig2(float v) {
    return __builtin_amdgcn_rcpf(1.0f + __builtin_amdgcn_exp2f(-v));
}
__device__ __forceinline__ float tanh2(float v) {
    return fmaf(2.0f, __builtin_amdgcn_rcpf(1.0f + __builtin_amdgcn_exp2f(-v)), -1.0f);
}

// chained MFMA: D = A*B + D
#define MFMA(ACC, AF, BF) \
    asm("v_mfma_f32_16x16x32_f16 %0, %1, %2, %0" : "+v"(ACC) : "v"(AF), "a"(BF))
// fresh-accumulator MFMA: D = A*B + Z (Z = pinned zero quad)
#define MFMA_Z(D, AF, BF, Z) \
    asm("v_mfma_f32_16x16x32_f16 %0, %1, %2, %3" : "=v"(D) : "v"(AF), "a"(BF), "v"(Z))

// LDS-only barrier (R15-R21 proven)
#define LBAR() asm volatile("s_waitcnt lgkmcnt(0)\n\ts_barrier" ::: "memory")

// ---- prepack W_hh -> f16 MFMA B-frags (R12-verified mapping) + exp2 prescale ----
__global__ void prepack_kernel(const float* __restrict__ W_hh, u32* __restrict__ wpk) {
    const int i = blockIdx.x * blockDim.x + threadIdx.x;
    if (i < 384 * 48) {
        const int r   = i & 3;
        const int u4  = i >> 2;
        const int tid = u4 / 12;
        const int f   = u4 % 12;
        const int g = f / 3, s = f % 3;
        const int l = tid & 63, u = tid >> 6;
        const int n = g * HID + u * 16 + (l & 15);
        const int k = s * 32 + ((l >> 4) & 3) * 8 + 2 * r;
        const float sc = (g == 2) ? K2 : L2E;
        wpk[i] = pk2(W_hh[n * HID + k] * sc, W_hh[n * HID + k + 1] * sc);
    }
}

__global__ __attribute__((amdgpu_flat_work_group_size(448, 448), amdgpu_waves_per_eu(1, 2)))
void lstm_mfma_kernel(const float* __restrict__ x,
                      const float* __restrict__ W_ih,
                      const float* __restrict__ b_ih,
                      const float* __restrict__ b_hh,
                      const float* __restrict__ W_fc,
                      const float* __restrict__ b_fc,
                      const u32x4* __restrict__ wpk4,
                      float* __restrict__ out)
{
    const int bo  = blockIdx.x * BT;
    const int tid = threadIdx.x;            // waves 0-5 workers, wave 6 FC
    const int l = tid & 63, u = tid >> 6;
    const bool isW = tid < 384;
    const int lg = l >> 4;                  // worker: k-subgroup / epilogue batch

    __shared__ __align__(16) __fp16 hbuf[2][BT][104];   // h state, row-pad 104
    __shared__ __align__(16) float  xs[2][BT];
    __shared__ __align__(16) float  fcp[BT][4];         // FC 4-way partials (same-step)

    for (int i = tid; i < 2 * BT * 104 / 2; i += 448) ((u32*)hbuf)[i] = 0u;
    if (tid < BT * 4) ((float*)fcp)[tid] = 0.0f;
    if (tid < BT) xs[0][tid] = x[bo + tid];

    const int jw = isW ? (u * 16 + (l & 15)) : 0;

    // B-frags: load once, pin to AGPRs (R12-proven residency)
    const u32x4* wp = wpk4 + (isW ? tid * 12 : 0);
    u32x4 b0 = wp[0], b1 = wp[1], b2  = wp[2],  b3  = wp[3];
    u32x4 b4 = wp[4], b5 = wp[5], b6  = wp[6],  b7  = wp[7];
    u32x4 b8 = wp[8], b9 = wp[9], b10 = wp[10], b11 = wp[11];
    asm volatile("" : "+a"(b0));  asm volatile("" : "+a"(b1));
    asm volatile("" : "+a"(b2));  asm volatile("" : "+a"(b3));
    asm volatile("" : "+a"(b4));  asm volatile("" : "+a"(b5));
    asm volatile("" : "+a"(b6));  asm volatile("" : "+a"(b7));
    asm volatile("" : "+a"(b8));  asm volatile("" : "+a"(b9));
    asm volatile("" : "+a"(b10)); asm volatile("" : "+a"(b11));

    // x-weights / biases, prescaled per gate (i,f,o: log2e; g: 2log2e)
    f32x4 wih4 = { W_ih[0*HID+jw] * L2E, W_ih[1*HID+jw] * L2E,
                   W_ih[2*HID+jw] * K2,  W_ih[3*HID+jw] * L2E };
    f32x4 bs4  = { (b_ih[0*HID+jw] + b_hh[0*HID+jw]) * L2E,
                   (b_ih[1*HID+jw] + b_hh[1*HID+jw]) * L2E,
                   (b_ih[2*HID+jw] + b_hh[2*HID+jw]) * K2,
                   (b_ih[3*HID+jw] + b_hh[3*HID+jw]) * L2E };
    asm volatile("" : "+v"(wih4)); asm volatile("" : "+v"(bs4));
    const float bfc = b_fc[0];

    // pinned zero quad: fresh-acc MFMA C-operand
    f32x4 zq = {0.f, 0.f, 0.f, 0.f};
    asm volatile("" : "+v"(zq));

    // FC wave: fm = l>>4 (batch), fp = l&15 (col group of 6 f16) -- R19 layout
    const int fm = l >> 4, fp = l & 15;
    u32 wf0 = 0, wf1 = 0, wf2 = 0;
    if (!isW) {
        wf0 = pk2(W_fc[fp*6+0], W_fc[fp*6+1]);
        wf1 = pk2(W_fc[fp*6+2], W_fc[fp*6+3]);
        wf2 = pk2(W_fc[fp*6+4], W_fc[fp*6+5]);
    }

    float c = 0.0f;                         // scaled cell state, batch lg, unit jw

    // parity-constant LDS pointers (R20)
    const __fp16* hr0 = &hbuf[0][(l & 15) >> 2][lg * 8];
    const __fp16* hr1 = &hbuf[1][(l & 15) >> 2][lg * 8];
    __fp16* hw0 = &hbuf[1][lg][jw];
    __fp16* hw1 = &hbuf[0][lg][jw];
    const u32* fr0 = (const u32*)&hbuf[0][fm][0] + fp * 3;
    const u32* fr1 = (const u32*)&hbuf[1][fm][0] + fp * 3;

    // FC x shift-chain: xO=x[t-1], xC=x[t], xP=x[t+1]
    float xO = 0.f, xC = 0.f, xP = 0.f;
    if (!isW) { xC = x[bo + fm]; xP = x[BATCH + bo + fm]; }
    __syncthreads();

// k-chain depth 2: (k0 -> k1 chained) + k2 fresh. The 4 independent k2 MFMAs
// are issued BETWEEN k0 and the dependent k1 -> their issue time covers k0's
// completion latency. One add/gate to combine (R21's depth-1 + 8 adds + setprio
// regressed; this is the single-variable version of the chain-depth cut).
#define WORK_BODY(P)                                                              \
    {                                                                             \
        const float xm = xs[P][lg];                                               \
        const __fp16* hr = (P) ? hr1 : hr0;                                       \
        const u32x4 a0 = *(const u32x4*)(hr);                                     \
        const u32x4 a1 = *(const u32x4*)(hr + 32);                                \
        const u32x4 a2 = *(const u32x4*)(hr + 64);                                \
        const float e0 = fmaf(xm, wih4[0], bs4[0]);                               \
        const float e1 = fmaf(xm, wih4[1], bs4[1]);                               \
        const float e2 = fmaf(xm, wih4[2], bs4[2]);                               \
        const float e3 = fmaf(xm, wih4[3], bs4[3]);                               \
        f32x4 acc0, acc1, acc2, acc3, q0, q1, q2, q3;                             \
        MFMA_Z(acc0, a0, b0, zq); MFMA_Z(acc1, a0, b3, zq);                       \
        MFMA_Z(acc2, a0, b6, zq); MFMA_Z(acc3, a0, b9, zq);                       \
        MFMA_Z(q0, a2, b2, zq);   MFMA_Z(q1, a2, b5, zq);                         \
        MFMA_Z(q2, a2, b8, zq);   MFMA_Z(q3, a2, b11, zq);                        \
        MFMA(acc0, a1, b1);  MFMA(acc1, a1, b4);                                  \
        MFMA(acc2, a1, b7);  MFMA(acc3, a1, b10);                                 \
        asm volatile("s_nop 7");                                                  \
        const float pi = acc0[0] + (q0[0] + e0);                                  \
        const float pf = acc1[0] + (q1[0] + e1);                                  \
        const float pg = acc2[0] + (q2[0] + e2);                                  \
        const float po = acc3[0] + (q3[0] + e3);                                  \
        const float gi = sig2(pi);                                                \
        const float gf = sig2(pf);                                                \
        const float gg = tanh2(pg);                                               \
        const float go = sig2(po);                                                \
        c = fmaf(gf, c, gi * gg * K2);                                            \
        const float hn = go * tanh2(c);                                           \
        *((P) ? hw1 : hw0) = (__fp16)hn;                                          \
    }

#define FC_BODY(P, T)                                                             \
    {                                                                             \
        if ((T) > 0) {                                                            \
            const u32* hp = (P) ? fr1 : fr0;                                      \
            const u32 hA = hp[0], hB = hp[1], hC = hp[2];                         \
            float s0 = fdot2u(wf0, hA, 0.0f);                                     \
            float s1 = fdot2u(wf1, hB, 0.0f);                                     \
            float s2 = fdot2u(wf2, hC, 0.0f);                                     \
            float p = (s0 + s1) + s2;                                             \
            p += __shfl_xor(p, 1);          /* DPP quad_perm */                   \
            p += __shfl_xor(p, 2);          /* DPP quad_perm */                   \
            if ((fp & 3) == 0) fcp[fm][fp >> 2] = p;                              \
            asm volatile("s_waitcnt lgkmcnt(0)" ::: "memory");                    \
            if (fp == 0) {                                                        \
                const float s = (fcp[fm][0] + fcp[fm][1]) + (fcp[fm][2] + fcp[fm][3]); \
                out[((T) - 1) * BATCH + bo + fm] = s + bfc + xO;                  \
            }                                                                     \
        }                                                                         \
        if (fp == 0) xs[(P) ^ 1][fm] = xP;                                        \
        xO = xC; xC = xP;                                                         \
        const int tn = ((T) + 2 < T_STEPS) ? ((T) + 2) : (T_STEPS - 1);           \
        xP = x[tn * BATCH + bo + fm];                                             \
    }

    for (int t = 0; t < T_STEPS; t += 2) {
        if (isW) WORK_BODY(0) else FC_BODY(0, t)
        LBAR();
        if (isW) WORK_BODY(1) else FC_BODY(1, t + 1)
        LBAR();
    }

    if (!isW) {   // tail: out[T-1] from h_T (hbuf[0]); xO = x[T-1]
        const u32 hA = fr0[0], hB = fr0[1], hC = fr0[2];
        float s0 = fdot2u(wf0, hA, 0.0f);
        float s1 = fdot2u(wf1, hB, 0.0f);
        float s2 = fdot2u(wf2, hC, 0.0f);
        float p = (s0 + s1) + s2;
        p += __shfl_xor(p, 1);
        p += __shfl_xor(p, 2);
        if ((fp & 3) == 0) fcp[fm][fp >> 2] = p;
        asm volatile("s_waitcnt lgkmcnt(0)" ::: "memory");
        if (fp == 0) {
            const float s = (fcp[fm][0] + fcp[fm][1]) + (fcp[fm][2] + fcp[fm][3]);
            out[(T_STEPS - 1) * BATCH + bo + fm] = s + bfc + xO;
        }
    }
}

extern "C" void kernel_launch(void* const* d_in, const int* in_sizes, int n_in,
                              void* d_out, int out_size, void* d_ws, size_t ws_size,
                              hipStream_t stream) {
    (void)in_sizes; (void)n_in; (void)out_size; (void)ws_size;
    const float* x    = (const float*)d_in[0];
    const float* W_ih = (const float*)d_in[1];
    const float* W_hh = (const float*)d_in[2];
    const float* b_ih = (const float*)d_in[3];
    const float* b_hh = (const float*)d_in[4];
    const float* W_fc = (const float*)d_in[5];
    const float* b_fc = (const float*)d_in[6];
    float* out = (float*)d_out;
    u32* wpk = (u32*)d_ws;                          // 384*48 u32 = 73728 B

    prepack_kernel<<<dim3((384 * 48 + 255) / 256), dim3(256), 0, stream>>>(W_hh, wpk);

    lstm_mfma_kernel<<<dim3(NBLK), dim3(448), 0, stream>>>(
        x, W_ih, b_ih, b_hh, W_fc, b_fc, (const u32x4*)wpk, out);
}